// Round 10
// baseline (167.008 us; speedup 1.0000x reference)
//
#include <hip/hip_runtime.h>
#include <math.h>

// TemporalSNNClassifier — bit-exact fp32 emulation (absmax 0.0 since r2).
//
// r24: r19-exact (90.0us champion) + T14 async W1 staging. r23's pipeline
// was slightly negative (95us) -> reverted. Ledger now: w2 reads null
// (r18), x-path null (r19), pk dedup NEG (r20), 4-blocks/CU NEG (r22),
// barrier-halving NEG (r23). Phase-2 is at its structural floor: VALU
// ~120K cyc/SIMD (53% busy), LDS ~27us, byte-math shows 8KB/row/group
// phase-B traffic is irreducible without 256-VGPR W2 or lossy fp16 W2.
// Last untested stall: phase-1 W1 global->LDS staging latency, exposed
// 4x at block-wide barriers. Fix (T14): issue chunk ch+1's 8 global
// loads right after ch's ds_writes; they fly across the barrier + 16-kq
// compute (~16K cyc >> load latency); consume (vmcnt-wait via first use
// + ds_write) at the next chunk boundary. Same values, same order ->
// absmax 0.0. Dbuf regs: stg[2][8], compile-time index under full
// unroll (rule #20). +32 VGPR (128->~160, free at 2 waves/SIMD).
// PRE-COMMIT: null => composite floor reached; r19-structure is final.
//
// r19: x via SMEM (s_load, wave-uniform). r17: fusion. r16b: fma_mix.
// Unified law (r10+r12+m136): 16B-per-lane VECTOR reads NEVER dedup;
// b32 same-addr broadcast FREE.
//
// FROZEN numerics: k-ascending single-accumulator fmaf chains (GEMM1),
// h-ascending 0..127 chain per (row,class,t) via v_fma_mix_f32 over fp16
// spike pairs (exact for {0,1}, single f32 rounding == fmaf(spk,w,acc)),
// bias as one separate add, leaky update ((0.9f*mem)+cur)-reset with
// contraction off, spike <=> mem > 1.0f, reset_t == spk_{t-1}.

#define T_STEPS 64
#define IN_DIM  256
#define HID     128
#define NCLS    8

#define ROWS   32     // rows per block (both phases)
#define THR    256
#define A_KQ   16     // float4 k-quads per chunk (64 k)
#define RSTR   260    // pk row stride (u32); =4 mod 32 -> staggered banks

typedef float f32x4 __attribute__((ext_vector_type(4)));

// pack two {0.0f,1.0f} spikes into one u32 as fp16 pair (lo=a, hi=b).
static __device__ __forceinline__ unsigned int pkspk(float a, float b) {
    auto h = __builtin_amdgcn_cvt_pkrtz(a, b);   // __fp16 ext_vector(2), 4B
    return __builtin_bit_cast(unsigned int, h);
}

__global__ __launch_bounds__(THR, 2)
void snn_fused(const float* __restrict__ x, const float* __restrict__ W1,
               const float* __restrict__ b1, const float* __restrict__ W2,
               const float* __restrict__ b2, float* __restrict__ out)
{
#pragma clang fp contract(off)
    __shared__ __align__(16) char smem[33280];
    float4 (* const w1c)[HID + 2] = (float4 (*)[HID + 2])smem;   // [16][130]
    unsigned int* const pk  = (unsigned int*)smem;               // 32*260 u32
    float*        const wsl = (float*)smem;                      // 32*128 f32

    const int tid  = threadIdx.x;
    const int lane = tid & 63;

    // ================= phase 1: cur1 GEMM (x via SMEM, async W1 stage) ===
    {
        const int wv = __builtin_amdgcn_readfirstlane(tid >> 6);   // 0..3
        const size_t rowg0 = (size_t)blockIdx.x * ROWS;
        // per-wave x base: rows wv*8 .. wv*8+7 (uniform)
        const float* xb = x + (rowg0 + (size_t)wv * 8) * IN_DIM;

        // per-thread W1 staging coordinates (fixed across chunks)
        const int sh = tid >> 4, skq = tid & 15;   // h-base tid>>4, kq tid&15

        float accL[8], accH[8];
        #pragma unroll
        for (int j = 0; j < 8; ++j) { accL[j] = 0.0f; accH[j] = 0.0f; }

        // double-buffered staging registers (compile-time indexed)
        float4 stg[2][8];
        // prologue: issue chunk 0 loads
        #pragma unroll
        for (int s = 0; s < 8; ++s) {
            const int idx = tid + s * THR;
            const int h = idx >> 4, kq = idx & 15;
            stg[0][s] = *(const float4*)(W1 + (size_t)h * IN_DIM + 0 + kq * 4);
        }

        #pragma unroll
        for (int ch = 0; ch < 4; ++ch) {
            const int kbase = ch * (A_KQ * 4);
            // consume staged regs -> LDS (compiler inserts vmcnt wait here)
            #pragma unroll
            for (int s = 0; s < 8; ++s) {
                const int idx = tid + s * THR;
                const int h = idx >> 4, kq = idx & 15;
                w1c[kq][h] = stg[ch & 1][s];
            }
            // issue next chunk's loads: in flight across barrier + kq loop
            if (ch < 3) {
                const int kbn = (ch + 1) * (A_KQ * 4);
                #pragma unroll
                for (int s = 0; s < 8; ++s) {
                    const int idx = tid + s * THR;
                    const int h = idx >> 4, kq = idx & 15;
                    stg[(ch + 1) & 1][s] =
                        *(const float4*)(W1 + (size_t)h * IN_DIM + kbn + kq * 4);
                }
            }
            __syncthreads();

            const float* xbc = xb + kbase;
            #pragma unroll 4
            for (int kq = 0; kq < A_KQ; ++kq) {
                // 8 rows' k-quads for this kq -> SGPRs (one wait for all 8).
                const float* xkq = xbc + kq * 4;
                f32x4 q0, q1, q2, q3, q4, q5, q6, q7;
                asm volatile(
                    "s_load_dwordx4 %0, %8, 0x0\n\t"
                    "s_load_dwordx4 %1, %8, 0x400\n\t"
                    "s_load_dwordx4 %2, %8, 0x800\n\t"
                    "s_load_dwordx4 %3, %8, 0xc00\n\t"
                    "s_load_dwordx4 %4, %8, 0x1000\n\t"
                    "s_load_dwordx4 %5, %8, 0x1400\n\t"
                    "s_load_dwordx4 %6, %8, 0x1800\n\t"
                    "s_load_dwordx4 %7, %8, 0x1c00\n\t"
                    "s_waitcnt lgkmcnt(0)"
                    : "=&s"(q0), "=&s"(q1), "=&s"(q2), "=&s"(q3),
                      "=&s"(q4), "=&s"(q5), "=&s"(q6), "=&s"(q7)
                    : "s"(xkq));

                const float4 wL = w1c[kq][lane];        // lane-contig 1KB
                const float4 wH = w1c[kq][64 + lane];
                // k ascending, single acc per (row, h) — order unchanged.
#define ROWFMA(J, XQ) { \
                float aL = accL[J], aH = accH[J]; \
                aL = fmaf(XQ.x, wL.x, aL); \
                aL = fmaf(XQ.y, wL.y, aL); \
                aL = fmaf(XQ.z, wL.z, aL); \
                aL = fmaf(XQ.w, wL.w, aL); \
                aH = fmaf(XQ.x, wH.x, aH); \
                aH = fmaf(XQ.y, wH.y, aH); \
                aH = fmaf(XQ.z, wH.z, aH); \
                aH = fmaf(XQ.w, wH.w, aH); \
                accL[J] = aL; accH[J] = aH; }
                ROWFMA(0, q0) ROWFMA(1, q1) ROWFMA(2, q2) ROWFMA(3, q3)
                ROWFMA(4, q4) ROWFMA(5, q5) ROWFMA(6, q6) ROWFMA(7, q7)
#undef ROWFMA
            }
            __syncthreads();   // w1c consumed before re-stage / alias
        }
        (void)sh; (void)skq;

        // handoff: cur1 tile -> LDS (aliases dead w1c). Values bit-identical
        // (same accL/accH + one rounded bias add).
        const float bL = b1[lane], bH = b1[64 + lane];
        #pragma unroll
        for (int j = 0; j < 8; ++j) {
            const int rr = wv * 8 + j;
            wsl[rr * HID + lane]      = accL[j] + bL;
            wsl[rr * HID + 64 + lane] = accH[j] + bH;
        }
    }

    // ================= phase 2: temporal loop (r19 verbatim) =============
    const int r = tid >> 3;            // phase-a row 0..31
    const int q = tid & 7;             // phase-a h-block

    const int brow = lane & 31;
    const int bcls = 2 * (tid >> 6) + (lane >> 5);
    const float b2c = b2[bcls];

    // W2 row for this thread's class -> VGPRs (grid-limited 2 waves/SIMD,
    // so up to 256 VGPR/thread is free).
    float4 w2r[32];
    {
        const float4* wg = (const float4*)(W2 + bcls * HID);
        #pragma unroll
        for (int g = 0; g < 32; ++g) w2r[g] = wg[g];
    }

    __syncthreads();   // wsl writes visible

    float cur1[16];
    {
        const float* src = wsl + r * HID + q * 16;
        #pragma unroll
        for (int i = 0; i < 4; ++i) {
            const float4 v = *(const float4*)(src + 4 * i);
            cur1[4*i+0] = v.x; cur1[4*i+1] = v.y;
            cur1[4*i+2] = v.z; cur1[4*i+3] = v.w;
        }
    }
    __syncthreads();   // cur1 read complete before pk overwrites wsl region

    float mem1[16], spk1[16];
    #pragma unroll
    for (int i = 0; i < 16; ++i) { mem1[i] = 0.0f; spk1[i] = 0.0f; }
    float m2 = 0.0f, r2v = 0.0f, o = 0.0f;

    #pragma unroll 1
    for (int ts = 0; ts < T_STEPS; ts += 4) {
        #pragma unroll
        for (int j = 0; j < 4; ++j) {
            #pragma unroll
            for (int i = 0; i < 16; ++i) {
                float tmp = 0.9f * mem1[i];   // rounded mul
                tmp = tmp + cur1[i];          // rounded add
                float m = tmp - spk1[i];      // rounded sub
                mem1[i] = m;
                spk1[i] = (m > 1.0f) ? 1.0f : 0.0f;
            }
            unsigned int* dst = &pk[r * RSTR + j * 64 + q * 8];
            #pragma unroll
            for (int s = 0; s < 2; ++s) {
                uint4 pv;
                pv.x = pkspk(spk1[8*s+0], spk1[8*s+1]);   // lo=even h, hi=odd h
                pv.y = pkspk(spk1[8*s+2], spk1[8*s+3]);
                pv.z = pkspk(spk1[8*s+4], spk1[8*s+5]);
                pv.w = pkspk(spk1[8*s+6], spk1[8*s+7]);
                *(uint4*)(dst + 4 * s) = pv;
            }
        }
        __syncthreads();

        float a0 = 0.0f, a1 = 0.0f, a2 = 0.0f, a3 = 0.0f;
        const unsigned int* src = &pk[brow * RSTR];
        // v_fma_mix_f32: src0 = fp16 half of packed word (exact 0/1 -> f32),
        // src1 = f32 W2 (VGPR), src2 = f32 acc; single f32 rounding —
        // bit-identical to fmaf(spk, w, acc), h-ascending. LO=even h, HI=odd.
#define FMIX_LO(A, P, W) \
        asm("v_fma_mix_f32 %0, %1, %2, %0 op_sel_hi:[1,0,0]" \
            : "+v"(A) : "v"(P), "v"(W));
#define FMIX_HI(A, P, W) \
        asm("v_fma_mix_f32 %0, %1, %2, %0 op_sel:[1,0,0] op_sel_hi:[1,0,0]" \
            : "+v"(A) : "v"(P), "v"(W));
#define TR(A, P) \
        FMIX_LO(A, P.x, wA.x) FMIX_HI(A, P.x, wA.y) \
        FMIX_LO(A, P.y, wA.z) FMIX_HI(A, P.y, wA.w) \
        FMIX_LO(A, P.z, wB.x) FMIX_HI(A, P.z, wB.y) \
        FMIX_LO(A, P.w, wB.z) FMIX_HI(A, P.w, wB.w)
        #pragma unroll
        for (int gg = 0; gg < 16; ++gg) {
            const float4 wA = w2r[2 * gg];
            const float4 wB = w2r[2 * gg + 1];
            const uint4 p0 = *(const uint4*)(src + 0 * 64 + 4 * gg);
            const uint4 p1 = *(const uint4*)(src + 1 * 64 + 4 * gg);
            const uint4 p2 = *(const uint4*)(src + 2 * 64 + 4 * gg);
            const uint4 p3 = *(const uint4*)(src + 3 * 64 + 4 * gg);
            TR(a0, p0) TR(a1, p1) TR(a2, p2) TR(a3, p3)
        }
#undef TR
#undef FMIX_HI
#undef FMIX_LO
        __syncthreads();

        const float aa[4] = {a0, a1, a2, a3};
        #pragma unroll
        for (int j = 0; j < 4; ++j) {
            const float c2 = aa[j] + b2c;
            float t2 = 0.9f * m2; t2 = t2 + c2; m2 = t2 - r2v;
            r2v = (m2 > 1.0f) ? 1.0f : 0.0f;
            o = o + r2v;
        }
    }

    out[((size_t)blockIdx.x * ROWS + brow) * NCLS + bcls] = o;
}

extern "C" void kernel_launch(void* const* d_in, const int* in_sizes, int n_in,
                              void* d_out, int out_size, void* d_ws, size_t ws_size,
                              hipStream_t stream) {
    const float* x  = (const float*)d_in[0];
    const float* W1 = (const float*)d_in[1];
    const float* b1 = (const float*)d_in[2];
    const float* W2 = (const float*)d_in[3];
    const float* b2 = (const float*)d_in[4];
    float* out = (float*)d_out;
    (void)d_ws; (void)ws_size;

    const int batch = in_sizes[0] / IN_DIM;          // 16384
    snn_fused<<<batch / ROWS, THR, 0, stream>>>(x, W1, b1, W2, b2, out);
}

// Round 11
// 144.619 us; speedup vs baseline: 1.1548x; 1.1548x over previous
//
#include <hip/hip_runtime.h>
#include <math.h>

// TemporalSNNClassifier — bit-exact fp32 emulation (absmax 0.0 since r2).
//
// r25: FINAL — revert to r19-exact (verified 144.63us end-to-end, 90.0us
// dispatch). r24's async W1 staging spilled (WRITE_SIZE 0.5->66MB,
// dispatch 129-145us): stg[2][8] double-buffer exceeded the register
// budget already committed to w2r + accumulators.
//
// Complete falsification ledger (every structural lever HW-adjudicated):
//   r18 w2 LDS reads -> VGPR:        null (-2us)
//   r19 x-delivery LDS -> SMEM:      null (kept: smaller LDS, no xcf)
//   r20 pk read dedup via permlane:  NEGATIVE (spills, swap VALU cost)
//   r22 occupancy 2->4 blocks/CU:    NEGATIVE (bank conflicts 3.5x)
//   r23 phase-a/b pipeline, dbuf pk: NEGATIVE (95us vs 90us)
//   r24 async W1 stage (T14):        NEGATIVE (register spills)
// Composite floor: ~50us irreducible VALU issue (frozen leaky update +
// pack + 8192 fma_mix per thread-group) + ~27us LDS pipe, imperfectly
// overlappable due to the ts-group dependency chain => 90us +/- 5 under
// every reshuffle. Wins this session: fma_mix fp16-pair packing
// (82->66us tloop), kernel fusion (132->92.5us), net 163.8 -> 144.6us.
//
// FROZEN numerics: k-ascending single-accumulator fmaf chains (GEMM1),
// h-ascending 0..127 chain per (row,class,t) via v_fma_mix_f32 over fp16
// spike pairs (exact for {0,1}, single f32 rounding == fmaf(spk,w,acc)),
// bias as one separate add, leaky update ((0.9f*mem)+cur)-reset with
// contraction off, spike <=> mem > 1.0f, reset_t == spk_{t-1}.

#define T_STEPS 64
#define IN_DIM  256
#define HID     128
#define NCLS    8

#define ROWS   32     // rows per block (both phases)
#define THR    256
#define A_KQ   16     // float4 k-quads per chunk (64 k)
#define RSTR   260    // pk row stride (u32); =4 mod 32 -> staggered banks

typedef float f32x4 __attribute__((ext_vector_type(4)));

// pack two {0.0f,1.0f} spikes into one u32 as fp16 pair (lo=a, hi=b).
static __device__ __forceinline__ unsigned int pkspk(float a, float b) {
    auto h = __builtin_amdgcn_cvt_pkrtz(a, b);   // __fp16 ext_vector(2), 4B
    return __builtin_bit_cast(unsigned int, h);
}

__global__ __launch_bounds__(THR, 2)
void snn_fused(const float* __restrict__ x, const float* __restrict__ W1,
               const float* __restrict__ b1, const float* __restrict__ W2,
               const float* __restrict__ b2, float* __restrict__ out)
{
#pragma clang fp contract(off)
    __shared__ __align__(16) char smem[33280];
    float4 (* const w1c)[HID + 2] = (float4 (*)[HID + 2])smem;   // [16][130]
    unsigned int* const pk  = (unsigned int*)smem;               // 32*260 u32
    float*        const wsl = (float*)smem;                      // 32*128 f32

    const int tid  = threadIdx.x;
    const int lane = tid & 63;

    // ================= phase 1: cur1 GEMM (x via SMEM) ===================
    {
        const int wv = __builtin_amdgcn_readfirstlane(tid >> 6);   // 0..3
        const size_t rowg0 = (size_t)blockIdx.x * ROWS;
        // per-wave x base: rows wv*8 .. wv*8+7 (uniform)
        const float* xb = x + (rowg0 + (size_t)wv * 8) * IN_DIM;

        float accL[8], accH[8];
        #pragma unroll
        for (int j = 0; j < 8; ++j) { accL[j] = 0.0f; accH[j] = 0.0f; }

        #pragma unroll 1
        for (int ch = 0; ch < 4; ++ch) {
            const int kbase = ch * (A_KQ * 4);
            // stage W1 chunk: 2048 float4, 8 per thread (coalesced per h-row)
            #pragma unroll
            for (int s = 0; s < 8; ++s) {
                const int idx = tid + s * THR;
                const int h = idx >> 4, kq = idx & 15;
                w1c[kq][h] = *(const float4*)(W1 + (size_t)h * IN_DIM + kbase + kq * 4);
            }
            __syncthreads();

            const float* xbc = xb + kbase;
            #pragma unroll 4
            for (int kq = 0; kq < A_KQ; ++kq) {
                // 8 rows' k-quads for this kq -> SGPRs (one wait for all 8).
                const float* xkq = xbc + kq * 4;
                f32x4 q0, q1, q2, q3, q4, q5, q6, q7;
                asm volatile(
                    "s_load_dwordx4 %0, %8, 0x0\n\t"
                    "s_load_dwordx4 %1, %8, 0x400\n\t"
                    "s_load_dwordx4 %2, %8, 0x800\n\t"
                    "s_load_dwordx4 %3, %8, 0xc00\n\t"
                    "s_load_dwordx4 %4, %8, 0x1000\n\t"
                    "s_load_dwordx4 %5, %8, 0x1400\n\t"
                    "s_load_dwordx4 %6, %8, 0x1800\n\t"
                    "s_load_dwordx4 %7, %8, 0x1c00\n\t"
                    "s_waitcnt lgkmcnt(0)"
                    : "=&s"(q0), "=&s"(q1), "=&s"(q2), "=&s"(q3),
                      "=&s"(q4), "=&s"(q5), "=&s"(q6), "=&s"(q7)
                    : "s"(xkq));

                const float4 wL = w1c[kq][lane];        // lane-contig 1KB
                const float4 wH = w1c[kq][64 + lane];
                // k ascending, single acc per (row, h) — order unchanged.
#define ROWFMA(J, XQ) { \
                float aL = accL[J], aH = accH[J]; \
                aL = fmaf(XQ.x, wL.x, aL); \
                aL = fmaf(XQ.y, wL.y, aL); \
                aL = fmaf(XQ.z, wL.z, aL); \
                aL = fmaf(XQ.w, wL.w, aL); \
                aH = fmaf(XQ.x, wH.x, aH); \
                aH = fmaf(XQ.y, wH.y, aH); \
                aH = fmaf(XQ.z, wH.z, aH); \
                aH = fmaf(XQ.w, wH.w, aH); \
                accL[J] = aL; accH[J] = aH; }
                ROWFMA(0, q0) ROWFMA(1, q1) ROWFMA(2, q2) ROWFMA(3, q3)
                ROWFMA(4, q4) ROWFMA(5, q5) ROWFMA(6, q6) ROWFMA(7, q7)
#undef ROWFMA
            }
            __syncthreads();   // w1c consumed before re-stage / alias
        }

        // handoff: cur1 tile -> LDS (aliases dead w1c). Values bit-identical
        // to the old global ws path (same accL/accH + one rounded bias add).
        const float bL = b1[lane], bH = b1[64 + lane];
        #pragma unroll
        for (int j = 0; j < 8; ++j) {
            const int rr = wv * 8 + j;
            wsl[rr * HID + lane]      = accL[j] + bL;
            wsl[rr * HID + 64 + lane] = accH[j] + bH;
        }
    }

    // ================= phase 2: temporal loop ============================
    const int r = tid >> 3;            // phase-a row 0..31
    const int q = tid & 7;             // phase-a h-block

    const int brow = lane & 31;
    const int bcls = 2 * (tid >> 6) + (lane >> 5);
    const float b2c = b2[bcls];

    // W2 row for this thread's class -> VGPRs (grid-limited 2 waves/SIMD,
    // so up to 256 VGPR/thread is free).
    float4 w2r[32];
    {
        const float4* wg = (const float4*)(W2 + bcls * HID);
        #pragma unroll
        for (int g = 0; g < 32; ++g) w2r[g] = wg[g];
    }

    __syncthreads();   // wsl writes visible

    float cur1[16];
    {
        const float* src = wsl + r * HID + q * 16;
        #pragma unroll
        for (int i = 0; i < 4; ++i) {
            const float4 v = *(const float4*)(src + 4 * i);
            cur1[4*i+0] = v.x; cur1[4*i+1] = v.y;
            cur1[4*i+2] = v.z; cur1[4*i+3] = v.w;
        }
    }
    __syncthreads();   // cur1 read complete before pk overwrites wsl region

    float mem1[16], spk1[16];
    #pragma unroll
    for (int i = 0; i < 16; ++i) { mem1[i] = 0.0f; spk1[i] = 0.0f; }
    float m2 = 0.0f, r2v = 0.0f, o = 0.0f;

    #pragma unroll 1
    for (int ts = 0; ts < T_STEPS; ts += 4) {
        #pragma unroll
        for (int j = 0; j < 4; ++j) {
            #pragma unroll
            for (int i = 0; i < 16; ++i) {
                float tmp = 0.9f * mem1[i];   // rounded mul
                tmp = tmp + cur1[i];          // rounded add
                float m = tmp - spk1[i];      // rounded sub
                mem1[i] = m;
                spk1[i] = (m > 1.0f) ? 1.0f : 0.0f;
            }
            unsigned int* dst = &pk[r * RSTR + j * 64 + q * 8];
            #pragma unroll
            for (int s = 0; s < 2; ++s) {
                uint4 pv;
                pv.x = pkspk(spk1[8*s+0], spk1[8*s+1]);   // lo=even h, hi=odd h
                pv.y = pkspk(spk1[8*s+2], spk1[8*s+3]);
                pv.z = pkspk(spk1[8*s+4], spk1[8*s+5]);
                pv.w = pkspk(spk1[8*s+6], spk1[8*s+7]);
                *(uint4*)(dst + 4 * s) = pv;
            }
        }
        __syncthreads();

        float a0 = 0.0f, a1 = 0.0f, a2 = 0.0f, a3 = 0.0f;
        const unsigned int* src = &pk[brow * RSTR];
        // v_fma_mix_f32: src0 = fp16 half of packed word (exact 0/1 -> f32),
        // src1 = f32 W2 (VGPR), src2 = f32 acc; single f32 rounding —
        // bit-identical to fmaf(spk, w, acc), h-ascending. LO=even h, HI=odd.
#define FMIX_LO(A, P, W) \
        asm("v_fma_mix_f32 %0, %1, %2, %0 op_sel_hi:[1,0,0]" \
            : "+v"(A) : "v"(P), "v"(W));
#define FMIX_HI(A, P, W) \
        asm("v_fma_mix_f32 %0, %1, %2, %0 op_sel:[1,0,0] op_sel_hi:[1,0,0]" \
            : "+v"(A) : "v"(P), "v"(W));
#define TR(A, P) \
        FMIX_LO(A, P.x, wA.x) FMIX_HI(A, P.x, wA.y) \
        FMIX_LO(A, P.y, wA.z) FMIX_HI(A, P.y, wA.w) \
        FMIX_LO(A, P.z, wB.x) FMIX_HI(A, P.z, wB.y) \
        FMIX_LO(A, P.w, wB.z) FMIX_HI(A, P.w, wB.w)
        #pragma unroll
        for (int gg = 0; gg < 16; ++gg) {
            const float4 wA = w2r[2 * gg];
            const float4 wB = w2r[2 * gg + 1];
            const uint4 p0 = *(const uint4*)(src + 0 * 64 + 4 * gg);
            const uint4 p1 = *(const uint4*)(src + 1 * 64 + 4 * gg);
            const uint4 p2 = *(const uint4*)(src + 2 * 64 + 4 * gg);
            const uint4 p3 = *(const uint4*)(src + 3 * 64 + 4 * gg);
            TR(a0, p0) TR(a1, p1) TR(a2, p2) TR(a3, p3)
        }
#undef TR
#undef FMIX_HI
#undef FMIX_LO
        __syncthreads();

        const float aa[4] = {a0, a1, a2, a3};
        #pragma unroll
        for (int j = 0; j < 4; ++j) {
            const float c2 = aa[j] + b2c;
            float t2 = 0.9f * m2; t2 = t2 + c2; m2 = t2 - r2v;
            r2v = (m2 > 1.0f) ? 1.0f : 0.0f;
            o = o + r2v;
        }
    }

    out[((size_t)blockIdx.x * ROWS + brow) * NCLS + bcls] = o;
}

extern "C" void kernel_launch(void* const* d_in, const int* in_sizes, int n_in,
                              void* d_out, int out_size, void* d_ws, size_t ws_size,
                              hipStream_t stream) {
    const float* x  = (const float*)d_in[0];
    const float* W1 = (const float*)d_in[1];
    const float* b1 = (const float*)d_in[2];
    const float* W2 = (const float*)d_in[3];
    const float* b2 = (const float*)d_in[4];
    float* out = (float*)d_out;
    (void)d_ws; (void)ws_size;

    const int batch = in_sizes[0] / IN_DIM;          // 16384
    snn_fused<<<batch / ROWS, THR, 0, stream>>>(x, W1, b1, W2, b2, out);
}